// Round 1
// baseline (145.829 us; speedup 1.0000x reference)
//
#include <hip/hip_runtime.h>

#define VOCAB 512
#define W 20
#define R_W 2            // rows per wave
#define WAVES 4          // 256-thread block = 4 independent waves
#define R (R_W * WAVES)  // 8 rows per block (grid shape unchanged vs prev best)

typedef float f4 __attribute__((ext_vector_type(4)));

// R5: wave-decoupled variant of the R4 best. Each 64-lane wave owns a private
// 4 KB LDS region (2 rows) and runs load -> zero -> ds_add scatter -> 4x
// nontemporal dwordx4 store with ZERO barriers: within-wave ds ordering is
// enforced by compiler lgkmcnt waits (same base pointer), and no cross-wave
// data exists. This removes the two __syncthreads (each = s_waitcnt vmcnt(0)
// lgkmcnt(0) + s_barrier) that forced the 4 waves into lockstep phases and
// made the per-CU store stream bursty. 32 independent wave-pipelines/CU keep
// nontemporal stores in flight continuously -> target the 22 us r+w floor.
__global__ __launch_bounds__(256) void fofe_kernel(
    const int*   __restrict__ sents,    // [rows * W]
    const int*   __restrict__ lengths,  // [B]
    const float* __restrict__ alpha_p,  // [1]
    float*       __restrict__ out,      // [rows * VOCAB + B]
    int rows, int B)
{
    __shared__ float lds[R * VOCAB];    // 16 KB total, 4 KB per wave

    const int tid  = threadIdx.x;
    const int wid  = tid >> 6;          // wave id 0..3
    const int lane = tid & 63;
    const int row0 = blockIdx.x * R + wid * R_W;   // this wave's first row

    float* wlds = lds + wid * (R_W * VOCAB);       // wave-private 4 KB

    // --- issue the char loads FIRST (long-latency), overlap with LDS zeroing ---
    float w = 0.f;
    int   c = 0;
    int   r = 0;
    if (lane < R_W * W) {               // 40 of 64 lanes
        r = lane / W;                   // row within wave (0..1)
        const int k = lane - r * W;     // char position
        c = sents[(size_t)(row0 + r) * W + k];     // block-coalesced 640 B load
        const float alpha = alpha_p[0];
        w = exp2f(log2f(alpha) * (float)(W - 1 - k));
        if (k == W - 1) w = 1.0f;       // alpha^0 == 1; dodges -inf*0 at alpha==0
    }

    // --- zero this wave's 4 KB: 4 x f4 per lane ---
    f4* l4 = (f4*)wlds;
    #pragma unroll
    for (int i = 0; i < 4; ++i)
        l4[lane + 64 * i] = (f4){0.f, 0.f, 0.f, 0.f};

    // no barrier: region is wave-private; lgkmcnt ordering covers write->atomic

    // --- scatter decay weights (ds_add_f32 handles duplicate chars) ---
    if (lane < R_W * W)
        atomicAdd(&wlds[r * VOCAB + c], w);

    // no barrier: lgkmcnt ordering covers atomic->read

    // --- contiguous 4 KB streaming write-out per wave: 4 x dwordx4 per lane ---
    f4* o4 = (f4*)(out + (size_t)row0 * VOCAB);
    #pragma unroll
    for (int i = 0; i < 4; ++i)
        __builtin_nontemporal_store(l4[lane + 64 * i], &o4[lane + 64 * i]);

    // --- output 1: lengths pass-through as float values at the tail ---
    if (blockIdx.x == 0 && tid < B) {
        out[(size_t)rows * VOCAB + tid] = (float)lengths[tid];
    }
}

extern "C" void kernel_launch(void* const* d_in, const int* in_sizes, int n_in,
                              void* d_out, int out_size, void* d_ws, size_t ws_size,
                              hipStream_t stream) {
    const int*   sents   = (const int*)d_in[0];    // [B*S*W] int32
    const int*   lengths = (const int*)d_in[1];    // [B] int32
    const float* alpha   = (const float*)d_in[2];  // [1] float32
    float*       out     = (float*)d_out;

    const int rows = in_sizes[0] / W;   // B*S = 65536
    const int B    = in_sizes[1];       // 256

    const int blocks = (rows + R - 1) / R;   // 8192
    fofe_kernel<<<blocks, 256, 0, stream>>>(sents, lengths, alpha, out, rows, B);
}

// Round 3
// 144.834 us; speedup vs baseline: 1.0069x; 1.0069x over previous
//
#include <hip/hip_runtime.h>
#include <hip/hip_bf16.h>

#define VOCAB 512
#define W 20
#define R 8   // rows per block

typedef float f4 __attribute__((ext_vector_type(4)));

// R7 = revert to R4 (best verified: 144.5 us, absmax 0.0).
// Evidence ledger for why this is final-form:
//  - R5 (barriers deleted): perf NEUTRAL (145.8 vs 144.5 = noise) and
//    absmax 2.64 (compiler hoisted store-feeding ds_reads above the ds_add
//    scatter). Barrier-phase-coupling theory is dead: with 8 resident
//    blocks/CU, inter-block jitter already keeps the store stream continuous.
//  - Window accounting: ~110 us of harness poison fills (537 MB d_ws @84 us
//    + 134 MB d_out @21 us) dominate; the fofe kernel itself is ~25-35 us
//    against a 22 us mandatory-traffic floor (134.2 MB write + 5.2 MB read
//    @ 6.3 TB/s). Remaining kernel headroom <10 us; fills are untouchable.
// Structure: 256-thread block builds R=8 consecutive rows in 16 KB LDS,
// then streams them out as one contiguous 16 KB burst (4 x dwordx4/thread).
// Stores issue once, at the end, with no trailing barrier — block exit
// overlaps store completion across the 8 resident blocks/CU.
__global__ __launch_bounds__(256) void fofe_kernel(
    const int*   __restrict__ sents,    // [rows * W]
    const int*   __restrict__ lengths,  // [B]
    const float* __restrict__ alpha_p,  // [1]
    float*       __restrict__ out,      // [rows * VOCAB + B]
    int rows, int B)
{
    __shared__ float lds[R * VOCAB];    // 16 KB

    const int tid  = threadIdx.x;
    const int row0 = blockIdx.x * R;

    // --- issue the char loads FIRST (long-latency), overlap with LDS zeroing ---
    float w = 0.f;
    int   c = 0;
    int   r = 0;
    if (tid < R * W) {
        r = tid / W;                       // row within block
        const int k = tid - r * W;         // char position
        c = sents[(size_t)(row0 + r) * W + k];   // coalesced 640 B block load
        const float alpha = alpha_p[0];
        w = exp2f(log2f(alpha) * (float)(W - 1 - k));
        if (k == W - 1) w = 1.0f;          // alpha^0 == 1; dodges -inf*0 at alpha==0
    }

    // --- zero 16 KB LDS: 4 x f4 per thread ---
    f4* l4 = (f4*)lds;
    #pragma unroll
    for (int i = 0; i < 4; ++i)
        l4[tid + 256 * i] = (f4){0.f, 0.f, 0.f, 0.f};

    __syncthreads();

    // --- scatter decay weights (ds_add_f32 handles duplicate chars) ---
    if (tid < R * W)
        atomicAdd(&lds[r * VOCAB + c], w);

    __syncthreads();

    // --- contiguous 16 KB streaming write-out: 4 x global_store_dwordx4 ---
    f4* o4 = (f4*)(out + (size_t)row0 * VOCAB);
    #pragma unroll
    for (int i = 0; i < 4; ++i)
        __builtin_nontemporal_store(l4[tid + 256 * i], &o4[tid + 256 * i]);

    // --- output 1: lengths pass-through as float values at the tail ---
    if (blockIdx.x == 0 && tid < B) {
        out[(size_t)rows * VOCAB + tid] = (float)lengths[tid];
    }
}

extern "C" void kernel_launch(void* const* d_in, const int* in_sizes, int n_in,
                              void* d_out, int out_size, void* d_ws, size_t ws_size,
                              hipStream_t stream) {
    const int*   sents   = (const int*)d_in[0];    // [B*S*W] int32
    const int*   lengths = (const int*)d_in[1];    // [B] int32
    const float* alpha   = (const float*)d_in[2];  // [1] float32
    float*       out     = (float*)d_out;

    const int rows = in_sizes[0] / W;   // B*S = 65536
    const int B    = in_sizes[1];       // 256

    const int blocks = (rows + R - 1) / R;   // 8192
    fofe_kernel<<<blocks, 256, 0, stream>>>(sents, lengths, alpha, out, rows, B);
}